// Round 1
// baseline (1320.722 us; speedup 1.0000x reference)
//
#include <hip/hip_runtime.h>
#include <hip/hip_bf16.h>

// graph_structure_learner: fused per-edge MLP + batchnorm + segment softmax.
// Round 1: fp32-VALU compute (W0 as bf16 pairs in LDS), 2-pass BN (recompute h),
// atomics for segment max/sum. ~5 MB workspace.

#define NREL_C   200
#define SLOPE    0.01f
#define THRESH_C 1e-4f
#define BN_EPS_C 1e-5f

__device__ __forceinline__ unsigned short f2bf(float f) {
    unsigned u = __float_as_uint(f);
    unsigned r = u + 0x7fffu + ((u >> 16) & 1u);   // round-to-nearest-even
    return (unsigned short)(r >> 16);
}

__device__ __forceinline__ unsigned enc_f32(float f) {
    unsigned u = __float_as_uint(f);
    return (u & 0x80000000u) ? ~u : (u | 0x80000000u);
}
__device__ __forceinline__ float dec_f32(unsigned k) {
    unsigned u = (k & 0x80000000u) ? (k & 0x7fffffffu) : ~k;
    return __uint_as_float(u);
}

// ---------------- init: zero stats + segment buffers ----------------
__global__ void init_kernel(double* g_sum, double* g_sq, unsigned* mkey, float* s, int n_nodes) {
    int idx = blockIdx.x * blockDim.x + threadIdx.x;
    if (idx < n_nodes) { mkey[idx] = 0u; s[idx] = 0.f; }
    if (idx < 128)     { g_sum[idx] = 0.0; g_sq[idx] = 0.0; }
}

// ---------------- rel projection: P[t][j] = b0[j] + rel[t]@W0[128:160] ----------------
__global__ void relproj_kernel(const float* __restrict__ rel, const float* __restrict__ W0,
                               const float* __restrict__ b0, float* __restrict__ P) {
    int idx = blockIdx.x * blockDim.x + threadIdx.x;
    if (idx >= NREL_C * 128) return;
    int t = idx >> 7, j = idx & 127;
    float acc = b0[j];
#pragma unroll
    for (int k = 0; k < 32; k++)
        acc = fmaf(rel[t * 32 + k], W0[(128 + k) * 128 + j], acc);
    P[idx] = acc;
}

// ---------------- stats finalize: A = gamma*rstd, B = beta - mu*A ----------------
__global__ void stats_kernel(const double* __restrict__ g_sum, const double* __restrict__ g_sq,
                             const float* __restrict__ gamma, const float* __restrict__ beta,
                             float* __restrict__ AB, int E) {
    int j = threadIdx.x;
    if (j < 128) {
        double mu  = g_sum[j] / (double)E;
        double var = g_sq[j] / (double)E - mu * mu;
        double rstd = 1.0 / sqrt(var + (double)BN_EPS_C);
        float A = (float)rstd * gamma[j];
        AB[j]       = A;
        AB[128 + j] = beta[j] - (float)mu * A;
    }
}

// ---------------- main pass: MODE 0 = stats, MODE 1 = w ----------------
// wave-per-8-edge tiles; W0 (K=128 rows x 128 cols) staged once to LDS as bf16 pairs.
template <int MODE>
__global__ __launch_bounds__(512, 4) void pass_kernel(
    const float* __restrict__ n_feat, const float* __restrict__ W0,
    const float* __restrict__ P, const int* __restrict__ row,
    const int* __restrict__ col, const int* __restrict__ etype,
    const float* __restrict__ AB, const float* __restrict__ W1,
    const float* __restrict__ b1, double* __restrict__ g_sum,
    double* __restrict__ g_sq, float* __restrict__ w_out, int E)
{
    __shared__ unsigned pkW0[128 * 64];   // 32 KB: {bf16 W0[i][l], bf16 W0[i][l+64]}
    __shared__ float4  sim4[8][256];      // 32 KB: per-wave 8 edges x 128 dims

    const int tid  = threadIdx.x;
    const int lane = tid & 63;
    const int wv   = tid >> 6;

    for (int idx = tid; idx < 128 * 64; idx += 512) {
        int i = idx >> 6, l = idx & 63;
        float wa = W0[i * 128 + l];
        float wb = W0[i * 128 + l + 64];
        pkW0[idx] = (unsigned)f2bf(wa) | ((unsigned)f2bf(wb) << 16);
    }
    __syncthreads();

    float4* mySim = sim4[wv];

    float A0 = 0, A1 = 0, B0 = 0, B1 = 0, w1a = 0, w1b = 0, b1v = 0;
    if (MODE == 1) {
        A0 = AB[lane]; A1 = AB[lane + 64];
        B0 = AB[128 + lane]; B1 = AB[128 + lane + 64];
        w1a = W1[lane]; w1b = W1[lane + 64];
        b1v = b1[0];
    }

    float sum0 = 0, sq0 = 0, sum1 = 0, sq1 = 0;

    const float4* nf4 = (const float4*)n_feat;
    const int ntiles = (E + 7) >> 3;
    const int gwave  = blockIdx.x * 8 + wv;
    const int nwaves = gridDim.x * 8;

    for (int t = gwave; t < ntiles; t += nwaves) {
        const int e0 = t << 3;

        // stage sim = exp(-|src-dst|) for 8 edges (2 edges per iter, float4 lanes)
#pragma unroll
        for (int ep = 0; ep < 8; ep += 2) {
            int eid = e0 + ep + (lane >> 5);
            int li  = lane & 31;
            float4 sv;
            if (eid < E) {
                int r = row[eid], c = col[eid];
                float4 a = nf4[(size_t)r * 32 + li];
                float4 b = nf4[(size_t)c * 32 + li];
                sv.x = __expf(-fabsf(a.x - b.x));
                sv.y = __expf(-fabsf(a.y - b.y));
                sv.z = __expf(-fabsf(a.z - b.z));
                sv.w = __expf(-fabsf(a.w - b.w));
            } else {
                sv = make_float4(0.f, 0.f, 0.f, 0.f);
            }
            mySim[(ep + (lane >> 5)) * 32 + li] = sv;
        }

        // init accumulators with rel projection (includes b0)
        float acc0[8], acc1[8];
#pragma unroll
        for (int e = 0; e < 8; e++) {
            int eid = e0 + e;
            if (eid < E) {
                int tt = etype[eid];
                acc0[e] = P[tt * 128 + lane];
                acc1[e] = P[tt * 128 + lane + 64];
            } else { acc0[e] = 0.f; acc1[e] = 0.f; }
        }

        // h[e][lane], h[e][lane+64] += sim[e][:] @ W0top  (wave-private, no barrier)
        for (int i0 = 0; i0 < 128; i0 += 4) {
            float wa[4], wb[4];
#pragma unroll
            for (int u = 0; u < 4; u++) {
                unsigned p = pkW0[(i0 + u) * 64 + lane];
                wa[u] = __uint_as_float(p << 16);
                wb[u] = __uint_as_float(p & 0xffff0000u);
            }
#pragma unroll
            for (int e = 0; e < 8; e++) {
                float4 s4 = mySim[e * 32 + (i0 >> 2)];
                acc0[e] = fmaf(s4.x, wa[0], acc0[e]);
                acc0[e] = fmaf(s4.y, wa[1], acc0[e]);
                acc0[e] = fmaf(s4.z, wa[2], acc0[e]);
                acc0[e] = fmaf(s4.w, wa[3], acc0[e]);
                acc1[e] = fmaf(s4.x, wb[0], acc1[e]);
                acc1[e] = fmaf(s4.y, wb[1], acc1[e]);
                acc1[e] = fmaf(s4.z, wb[2], acc1[e]);
                acc1[e] = fmaf(s4.w, wb[3], acc1[e]);
            }
        }

        if (MODE == 0) {
#pragma unroll
            for (int e = 0; e < 8; e++) {
                sum0 += acc0[e]; sq0 = fmaf(acc0[e], acc0[e], sq0);
                sum1 += acc1[e]; sq1 = fmaf(acc1[e], acc1[e], sq1);
            }
        } else {
#pragma unroll
            for (int e = 0; e < 8; e++) {
                int eid = e0 + e;
                float h0 = fmaf(acc0[e], A0, B0);
                float h1 = fmaf(acc1[e], A1, B1);
                h0 = h0 >= 0.f ? h0 : SLOPE * h0;
                h1 = h1 >= 0.f ? h1 : SLOPE * h1;
                float p = h0 * w1a + h1 * w1b;
#pragma unroll
                for (int off = 32; off; off >>= 1) p += __shfl_down(p, off);
                if (lane == 0 && eid < E) w_out[eid] = p + b1v;
            }
        }
    }

    if (MODE == 0) {
        __syncthreads();                      // sim tiles no longer needed
        float* redS = (float*)sim4;           // [8][128]
        float* redQ = ((float*)sim4) + 1024;  // [8][128]
        redS[wv * 128 + lane]      = sum0;
        redS[wv * 128 + lane + 64] = sum1;
        redQ[wv * 128 + lane]      = sq0;
        redQ[wv * 128 + lane + 64] = sq1;
        __syncthreads();
        if (tid < 128) {
            double ts = 0, tq = 0;
#pragma unroll
            for (int w8 = 0; w8 < 8; w8++) {
                ts += (double)redS[w8 * 128 + tid];
                tq += (double)redQ[w8 * 128 + tid];
            }
            atomicAdd(&g_sum[tid], ts);
            atomicAdd(&g_sq[tid], tq);
        }
    }
}

// ---------------- original-edge blend: w = (1-l)*w + l, l = 0.5 ----------------
__global__ void ori_kernel(const int* __restrict__ ori, float* __restrict__ w, int n_ori) {
    int i = blockIdx.x * blockDim.x + threadIdx.x;
    if (i < n_ori) { int e = ori[i]; w[e] = fmaf(w[e], 0.5f, 0.5f); }
}

// ---------------- segment max over col ----------------
__global__ void segmax_kernel(const float* __restrict__ w, const int* __restrict__ col,
                              unsigned* __restrict__ mkey, int E) {
    int i = blockIdx.x * blockDim.x + threadIdx.x;
    if (i < E) atomicMax(&mkey[col[i]], enc_f32(w[i]));
}

// ---------------- e = exp(w - m[col]); s[col] += e ----------------
__global__ void exp_kernel(const float* __restrict__ w, const int* __restrict__ col,
                           const unsigned* __restrict__ mkey, float* __restrict__ s,
                           float* __restrict__ out, int E) {
    int i = blockIdx.x * blockDim.x + threadIdx.x;
    if (i < E) {
        int c = col[i];
        float m = dec_f32(mkey[c]);
        float e = __expf(w[i] - m);
        out[i] = e;
        atomicAdd(&s[c], e);
    }
}

// ---------------- normalize + threshold ----------------
__global__ void norm_kernel(const int* __restrict__ col, const float* __restrict__ s,
                            float* __restrict__ out, int E) {
    int i = blockIdx.x * blockDim.x + threadIdx.x;
    if (i < E) {
        float v = out[i] / s[col[i]];
        out[i] = v > THRESH_C ? v : 0.f;
    }
}

extern "C" void kernel_launch(void* const* d_in, const int* in_sizes, int n_in,
                              void* d_out, int out_size, void* d_ws, size_t ws_size,
                              hipStream_t stream) {
    const float* n_feat = (const float*)d_in[0];
    const float* rel    = (const float*)d_in[1];
    const float* W0     = (const float*)d_in[2];
    const float* b0     = (const float*)d_in[3];
    const float* gamma  = (const float*)d_in[4];
    const float* beta   = (const float*)d_in[5];
    const float* W1     = (const float*)d_in[6];
    const float* b1     = (const float*)d_in[7];
    const int*   row    = (const int*)d_in[8];
    const int*   col    = (const int*)d_in[9];
    const int*   etype  = (const int*)d_in[10];
    const int*   ori    = (const int*)d_in[11];

    const int E    = in_sizes[8];
    const int Nn   = in_sizes[0] / 128;
    const int nOri = in_sizes[11];
    float* out = (float*)d_out;

    char* ws = (char*)d_ws;
    double*   g_sum = (double*)(ws + 0);
    double*   g_sq  = (double*)(ws + 1024);
    float*    AB    = (float*)(ws + 2048);
    float*    P     = (float*)(ws + 3072);
    size_t    off_w = 3072 + (size_t)NREL_C * 128 * 4;          // 105472
    float*    wbuf  = (float*)(ws + off_w);
    size_t    off_m = off_w + 4 * (size_t)E;
    unsigned* mkey  = (unsigned*)(ws + off_m);
    float*    sbuf  = (float*)(ws + off_m + 4 * (size_t)Nn);

    int nbN = (max(Nn, 128) + 255) / 256;
    init_kernel<<<nbN, 256, 0, stream>>>(g_sum, g_sq, mkey, sbuf, Nn);

    int nbP = (NREL_C * 128 + 255) / 256;
    relproj_kernel<<<nbP, 256, 0, stream>>>(rel, W0, b0, P);

    pass_kernel<0><<<512, 512, 0, stream>>>(n_feat, W0, P, row, col, etype,
                                            AB, W1, b1, g_sum, g_sq, wbuf, E);

    stats_kernel<<<1, 128, 0, stream>>>(g_sum, g_sq, gamma, beta, AB, E);

    pass_kernel<1><<<512, 512, 0, stream>>>(n_feat, W0, P, row, col, etype,
                                            AB, W1, b1, g_sum, g_sq, wbuf, E);

    int nbO = (nOri + 255) / 256;
    ori_kernel<<<nbO, 256, 0, stream>>>(ori, wbuf, nOri);

    int nbE = (E + 255) / 256;
    segmax_kernel<<<nbE, 256, 0, stream>>>(wbuf, col, mkey, E);
    exp_kernel<<<nbE, 256, 0, stream>>>(wbuf, col, mkey, sbuf, out, E);
    norm_kernel<<<nbE, 256, 0, stream>>>(col, sbuf, out, E);
}

// Round 2
// 531.359 us; speedup vs baseline: 2.4856x; 2.4856x over previous
//
#include <hip/hip_runtime.h>
#include <hip/hip_bf16.h>

// graph_structure_learner round 2: MFMA-based MLP (K=160 incl. rel dims),
// 2-pass BN (recompute), XOR-swizzled LDS A-tiles, W0^T held in registers.

#define SLOPE    0.01f
#define THRESH_C 1e-4f
#define BN_EPS_C 1e-5f

typedef __bf16 bf16x8 __attribute__((ext_vector_type(8)));
typedef float  f32x4  __attribute__((ext_vector_type(4)));

__device__ __forceinline__ unsigned short f2bf(float f) {
    unsigned u = __float_as_uint(f);
    unsigned r = u + 0x7fffu + ((u >> 16) & 1u);   // RNE
    return (unsigned short)(r >> 16);
}
__device__ __forceinline__ unsigned pk2(float a, float b) {
    return (unsigned)f2bf(a) | ((unsigned)f2bf(b) << 16);
}

__device__ __forceinline__ unsigned enc_f32(float f) {
    unsigned u = __float_as_uint(f);
    return (u & 0x80000000u) ? ~u : (u | 0x80000000u);
}
__device__ __forceinline__ float dec_f32(unsigned k) {
    unsigned u = (k & 0x80000000u) ? (k & 0x7fffffffu) : ~k;
    return __uint_as_float(u);
}

// ---------------- init: zero stats + segment buffers ----------------
__global__ void init_kernel(double* g_sum, double* g_sq, unsigned* mkey, float* s, int n_nodes) {
    int idx = blockIdx.x * blockDim.x + threadIdx.x;
    if (idx < n_nodes) { mkey[idx] = 0u; s[idx] = 0.f; }
    if (idx < 1024)    { g_sum[idx] = 0.0; g_sq[idx] = 0.0; }   // 8 replicas x 128
}

// ---------------- stats finalize: A = gamma*rstd, B = beta - mu*A ----------------
__global__ void stats_kernel(const double* __restrict__ g_sum, const double* __restrict__ g_sq,
                             const float* __restrict__ gamma, const float* __restrict__ beta,
                             float* __restrict__ AB, int E) {
    int j = threadIdx.x;
    if (j < 128) {
        double s = 0.0, q = 0.0;
#pragma unroll
        for (int r = 0; r < 8; r++) { s += g_sum[r * 128 + j]; q += g_sq[r * 128 + j]; }
        double mu  = s / (double)E;
        double var = q / (double)E - mu * mu;
        double rstd = 1.0 / sqrt(var + (double)BN_EPS_C);
        float A = (float)rstd * gamma[j];
        AB[j]       = A;
        AB[128 + j] = beta[j] - (float)mu * A;
    }
}

// ---------------- main pass: MODE 0 = stats, MODE 1 = w ----------------
// 64-edge tiles; A = [sim | rel] bf16 in LDS (row stride 384 B, XOR-swizzled);
// B = W0^T (160x128) in registers (20 frags/wave); waves split 1x4 over cols.
template <int MODE>
__global__ __launch_bounds__(256, 3) void pass_kernel(
    const float* __restrict__ n_feat, const float* __restrict__ W0,
    const float* __restrict__ rel, const float* __restrict__ b0,
    const int* __restrict__ row, const int* __restrict__ col,
    const int* __restrict__ etype, const float* __restrict__ AB,
    const float* __restrict__ W1, const float* __restrict__ b1,
    double* __restrict__ g_sum, double* __restrict__ g_sq,
    float* __restrict__ w_out, int E, int ntiles)
{
    __shared__ __align__(16) char lds[128 * 320];   // 40 KB: Wt at init, then A(24576)+wsum

    const int tid  = threadIdx.x;
    const int lane = tid & 63;
    const int wv   = tid >> 6;
    const int grp  = lane >> 4;
    const int l15  = lane & 15;

    // ---- stage W0^T (bf16) to LDS, pull B fragments into registers ----
    for (int idx = tid; idx < 160 * 128; idx += 256) {
        int k = idx >> 7, cc = idx & 127;
        *(unsigned short*)(lds + cc * 320 + k * 2) = f2bf(W0[idx]);
    }
    __syncthreads();
    bf16x8 bf[2][5];
#pragma unroll
    for (int ct = 0; ct < 2; ct++) {
        int bcol = wv * 32 + ct * 16 + l15;
#pragma unroll
        for (int ks = 0; ks < 5; ks++)
            bf[ct][ks] = *(const bf16x8*)(lds + bcol * 320 + ks * 64 + grp * 16);
    }
    __syncthreads();

    float b0v[2], A0v[2] = {0, 0}, B0v[2] = {0, 0}, W1v[2] = {0, 0}, b1v = 0.f;
#pragma unroll
    for (int ct = 0; ct < 2; ct++) {
        int c = wv * 32 + ct * 16 + l15;
        b0v[ct] = b0[c];
        if (MODE == 1) { A0v[ct] = AB[c]; B0v[ct] = AB[128 + c]; W1v[ct] = W1[c]; }
    }
    if (MODE == 1) b1v = b1[0];

    float sums[2] = {0, 0}, sqs[2] = {0, 0};

    char*  Ab   = lds;                        // 64 rows x 384 B
    float* wsum = (float*)(lds + 24576);      // [4][64]

    const float4* nf4 = (const float4*)n_feat;
    const int e_loc = tid >> 2, q = tid & 3;
    char* wr_base = Ab + e_loc * 384;
    const unsigned sw = (unsigned)(e_loc & 7) << 4;

    int prev_base = 0; bool have_prev = false;

    for (int t = blockIdx.x; t < ntiles; t += gridDim.x) {
        const int ebase = t << 6;

        // -------- stage: sim=exp(-|src-dst|) + rel, bf16, swizzled --------
        {
            const int eid = ebase + e_loc;
            unsigned simw[16], relw[4];
            if (eid < E) {
                const int r = row[eid], c = col[eid], ty = etype[eid];
                const float4* ra = nf4 + (size_t)r * 32 + q * 8;
                const float4* rb = nf4 + (size_t)c * 32 + q * 8;
#pragma unroll
                for (int i = 0; i < 8; i++) {
                    float4 a = ra[i], b = rb[i];
                    float s0 = __expf(-fabsf(a.x - b.x));
                    float s1 = __expf(-fabsf(a.y - b.y));
                    float s2 = __expf(-fabsf(a.z - b.z));
                    float s3 = __expf(-fabsf(a.w - b.w));
                    simw[2 * i]     = pk2(s0, s1);
                    simw[2 * i + 1] = pk2(s2, s3);
                }
                const float4* rr = (const float4*)(rel + (size_t)ty * 32 + q * 8);
                float4 r0 = rr[0], r1 = rr[1];
                relw[0] = pk2(r0.x, r0.y); relw[1] = pk2(r0.z, r0.w);
                relw[2] = pk2(r1.x, r1.y); relw[3] = pk2(r1.z, r1.w);
            } else {
#pragma unroll
                for (int i = 0; i < 16; i++) simw[i] = 0u;
                relw[0] = relw[1] = relw[2] = relw[3] = 0u;
            }
#pragma unroll
            for (int wq = 0; wq < 4; wq++)
                *(uint4*)(wr_base + (((unsigned)(q * 64 + wq * 16)) ^ sw)) =
                    make_uint4(simw[4 * wq], simw[4 * wq + 1], simw[4 * wq + 2], simw[4 * wq + 3]);
            *(uint4*)(wr_base + (((unsigned)(256 + q * 16)) ^ sw)) =
                make_uint4(relw[0], relw[1], relw[2], relw[3]);
        }

        // combine previous tile's per-wave partials -> w (overlaps staging)
        if (MODE == 1 && have_prev && tid < 64) {
            int e = prev_base + tid;
            if (e < E)
                w_out[e] = wsum[tid] + wsum[64 + tid] + wsum[128 + tid] + wsum[192 + tid] + b1v;
        }
        __syncthreads();

        // -------- compute: h = [sim|rel] @ W0 + b0 via MFMA --------
        f32x4 acc[4][2];
#pragma unroll
        for (int rt = 0; rt < 4; rt++)
#pragma unroll
            for (int ct = 0; ct < 2; ct++)
                acc[rt][ct] = {b0v[ct], b0v[ct], b0v[ct], b0v[ct]};

#pragma unroll
        for (int rt = 0; rt < 4; rt++) {
            const int arow = rt * 16 + l15;
            const char* rbp = Ab + arow * 384;
            const unsigned asw = (unsigned)(arow & 7) << 4;
            bf16x8 a[5];
#pragma unroll
            for (int ks = 0; ks < 5; ks++)
                a[ks] = *(const bf16x8*)(rbp + (((unsigned)(ks * 64 + grp * 16)) ^ asw));
#pragma unroll
            for (int ct = 0; ct < 2; ct++)
#pragma unroll
                for (int ks = 0; ks < 5; ks++)
                    acc[rt][ct] = __builtin_amdgcn_mfma_f32_16x16x32_bf16(
                        a[ks], bf[ct][ks], acc[rt][ct], 0, 0, 0);
        }

        if (MODE == 0) {
            if (ebase + 64 <= E) {
#pragma unroll
                for (int rt = 0; rt < 4; rt++)
#pragma unroll
                    for (int ct = 0; ct < 2; ct++) {
                        f32x4 h = acc[rt][ct];
#pragma unroll
                        for (int rg = 0; rg < 4; rg++) {
                            sums[ct] += h[rg];
                            sqs[ct]  = fmaf(h[rg], h[rg], sqs[ct]);
                        }
                    }
            } else {
#pragma unroll
                for (int rt = 0; rt < 4; rt++)
#pragma unroll
                    for (int rg = 0; rg < 4; rg++) {
                        int eid = ebase + rt * 16 + grp * 4 + rg;
                        float m = (eid < E) ? 1.f : 0.f;
#pragma unroll
                        for (int ct = 0; ct < 2; ct++) {
                            float h = acc[rt][ct][rg] * m;
                            sums[ct] += h;
                            sqs[ct]  = fmaf(h, h, sqs[ct]);
                        }
                    }
            }
        } else {
            // epilogue: BN affine -> LeakyReLU -> *W1 -> col-reduce -> wsum
#pragma unroll
            for (int rt = 0; rt < 4; rt++) {
#pragma unroll
                for (int rg = 0; rg < 4; rg++) {
                    float v = 0.f;
#pragma unroll
                    for (int ct = 0; ct < 2; ct++) {
                        float h = fmaf(acc[rt][ct][rg], A0v[ct], B0v[ct]);
                        h = h >= 0.f ? h : SLOPE * h;
                        v = fmaf(h, W1v[ct], v);
                    }
                    v += __shfl_xor(v, 1); v += __shfl_xor(v, 2);
                    v += __shfl_xor(v, 4); v += __shfl_xor(v, 8);
                    if (l15 == 0) wsum[wv * 64 + rt * 16 + grp * 4 + rg] = v;
                }
            }
            prev_base = ebase; have_prev = true;
        }
        __syncthreads();
    }

    if (MODE == 1 && have_prev && tid < 64) {
        int e = prev_base + tid;
        if (e < E)
            w_out[e] = wsum[tid] + wsum[64 + tid] + wsum[128 + tid] + wsum[192 + tid] + b1v;
    }

    if (MODE == 0) {
#pragma unroll
        for (int ct = 0; ct < 2; ct++) {
            sums[ct] += __shfl_xor(sums[ct], 16); sums[ct] += __shfl_xor(sums[ct], 32);
            sqs[ct]  += __shfl_xor(sqs[ct], 16);  sqs[ct]  += __shfl_xor(sqs[ct], 32);
        }
        if (lane < 16) {
            int rep = blockIdx.x & 7;
#pragma unroll
            for (int ct = 0; ct < 2; ct++) {
                int c = wv * 32 + ct * 16 + lane;
                atomicAdd(&g_sum[rep * 128 + c], (double)sums[ct]);
                atomicAdd(&g_sq[rep * 128 + c], (double)sqs[ct]);
            }
        }
    }
}

// ---------------- original-edge blend: w = 0.5*w + 0.5 ----------------
__global__ void ori_kernel(const int* __restrict__ ori, float* __restrict__ w, int n_ori) {
    int i = blockIdx.x * blockDim.x + threadIdx.x;
    if (i < n_ori) { int e = ori[i]; w[e] = fmaf(w[e], 0.5f, 0.5f); }
}

// ---------------- segment max over col ----------------
__global__ void segmax_kernel(const float* __restrict__ w, const int* __restrict__ col,
                              unsigned* __restrict__ mkey, int E) {
    int i = blockIdx.x * blockDim.x + threadIdx.x;
    if (i < E) atomicMax(&mkey[col[i]], enc_f32(w[i]));
}

// ---------------- e = exp(w - m[col]); s[col] += e ----------------
__global__ void exp_kernel(const float* __restrict__ w, const int* __restrict__ col,
                           const unsigned* __restrict__ mkey, float* __restrict__ s,
                           float* __restrict__ out, int E) {
    int i = blockIdx.x * blockDim.x + threadIdx.x;
    if (i < E) {
        int c = col[i];
        float m = dec_f32(mkey[c]);
        float e = __expf(w[i] - m);
        out[i] = e;
        atomicAdd(&s[c], e);
    }
}

// ---------------- normalize + threshold ----------------
__global__ void norm_kernel(const int* __restrict__ col, const float* __restrict__ s,
                            float* __restrict__ out, int E) {
    int i = blockIdx.x * blockDim.x + threadIdx.x;
    if (i < E) {
        float v = out[i] / s[col[i]];
        out[i] = v > THRESH_C ? v : 0.f;
    }
}

extern "C" void kernel_launch(void* const* d_in, const int* in_sizes, int n_in,
                              void* d_out, int out_size, void* d_ws, size_t ws_size,
                              hipStream_t stream) {
    const float* n_feat = (const float*)d_in[0];
    const float* rel    = (const float*)d_in[1];
    const float* W0     = (const float*)d_in[2];
    const float* b0     = (const float*)d_in[3];
    const float* gamma  = (const float*)d_in[4];
    const float* beta   = (const float*)d_in[5];
    const float* W1     = (const float*)d_in[6];
    const float* b1     = (const float*)d_in[7];
    const int*   row    = (const int*)d_in[8];
    const int*   col    = (const int*)d_in[9];
    const int*   etype  = (const int*)d_in[10];
    const int*   ori    = (const int*)d_in[11];

    const int E    = in_sizes[8];
    const int Nn   = in_sizes[0] / 128;
    const int nOri = in_sizes[11];
    float* out = (float*)d_out;

    char* ws = (char*)d_ws;
    double*   g_sum = (double*)(ws + 0);          // 8 x 128 doubles
    double*   g_sq  = (double*)(ws + 8192);       // 8 x 128 doubles
    float*    AB    = (float*)(ws + 16384);       // 256 f32
    float*    wbuf  = (float*)(ws + 17408);       // E f32
    size_t    off_m = 17408 + 4 * (size_t)E;
    unsigned* mkey  = (unsigned*)(ws + off_m);
    float*    sbuf  = (float*)(ws + off_m + 4 * (size_t)Nn);

    int nbN = ((Nn > 1024 ? Nn : 1024) + 255) / 256;
    init_kernel<<<nbN, 256, 0, stream>>>(g_sum, g_sq, mkey, sbuf, Nn);

    const int ntiles = (E + 63) >> 6;
    const int grid_p = ntiles < 768 ? ntiles : 768;

    pass_kernel<0><<<grid_p, 256, 0, stream>>>(n_feat, W0, rel, b0, row, col, etype,
                                               AB, W1, b1, g_sum, g_sq, wbuf, E, ntiles);

    stats_kernel<<<1, 128, 0, stream>>>(g_sum, g_sq, gamma, beta, AB, E);

    pass_kernel<1><<<grid_p, 256, 0, stream>>>(n_feat, W0, rel, b0, row, col, etype,
                                               AB, W1, b1, g_sum, g_sq, wbuf, E, ntiles);

    int nbO = (nOri + 255) / 256;
    ori_kernel<<<nbO, 256, 0, stream>>>(ori, wbuf, nOri);

    int nbE = (E + 255) / 256;
    segmax_kernel<<<nbE, 256, 0, stream>>>(wbuf, col, mkey, E);
    exp_kernel<<<nbE, 256, 0, stream>>>(wbuf, col, mkey, sbuf, out, E);
    norm_kernel<<<nbE, 256, 0, stream>>>(col, sbuf, out, E);
}